// Round 1
// baseline (413.510 us; speedup 1.0000x reference)
//
#include <hip/hip_runtime.h>

// Problem: N=32, C=512, H=W=32 (HW=1024), D=256.
// out = x + W_fuse * softmax((Wt x)^T (Wp x) / 16) applied to values x, per batch.
//
// Pipeline (all bf16 MFMA, fp32 accumulate):
//  k_packw : W_theta|W_phi -> Wcat bf16 [512][512], W_fuse -> bf16 [512][512]
//  k_prep  : x [n,c,q] fp32 -> xt [n,q,c] bf16 (transposed, pixel-major)
//  k_embed : tp[n,q,0:256]=theta, [256:512]=phi  (GEMM 32768x512x512)
//  k_attn  : per (n, 32-query tile): S=Q K^T/16, P=exp(S) in LDS, rowsums,
//            O = P V^T / rowsum -> at[n,q,c] bf16  (V = x, fp32->bf16 on the fly)
//  k_fuse  : out[n,o,q] = x + b_fuse[o] + sum_c W_fuse[o,c] at[n,q,c] (fp32 out)
//
// Workspace layout (needs 65 MB):
//   [0,32MB)    xt  (reused as `at` after k_embed consumed it)
//   [32,64MB)   tp
//   [64MB, +512K)  Wcat bf16
//   [+512K, +1MB)  Wfuse bf16

#define NB  32
#define CC  512
#define HWD 1024

typedef __attribute__((ext_vector_type(8))) short short8;
typedef __attribute__((ext_vector_type(4))) float f32x4;

__device__ __forceinline__ unsigned short f2bu(float f) {
    unsigned int u = __float_as_uint(f);
    u = (u + 0x7FFFu + ((u >> 16) & 1u)) >> 16;   // RNE to bf16
    return (unsigned short)u;
}

// ---------------- weights pack ----------------
__global__ __launch_bounds__(256) void k_packw(const float* __restrict__ Wt,
                                               const float* __restrict__ Wp,
                                               const float* __restrict__ Wf,
                                               unsigned short* __restrict__ Wcat,
                                               unsigned short* __restrict__ Wfuse) {
    int idx = blockIdx.x * 256 + threadIdx.x;       // 0 .. 262143
    int o = idx >> 9;
    float cv = (o < 256) ? Wt[idx] : Wp[idx - 131072];
    Wcat[idx]  = f2bu(cv);
    Wfuse[idx] = f2bu(Wf[idx]);
}

// ---------------- x transpose -> xt[n,q,c] bf16 ----------------
__global__ __launch_bounds__(256) void k_prep(const float* __restrict__ x,
                                              unsigned short* __restrict__ xt) {
    __shared__ float tile[32][33];
    const int n = blockIdx.z, c0 = blockIdx.y << 5, q0 = blockIdx.x << 5;
    const int t = threadIdx.x;
    const int r = t >> 3, j4 = (t & 7) << 2;
    const float* src = x + ((size_t)(n * CC + c0 + r)) * HWD + q0 + j4;
    float4 v = *(const float4*)src;
    tile[r][j4 + 0] = v.x; tile[r][j4 + 1] = v.y;
    tile[r][j4 + 2] = v.z; tile[r][j4 + 3] = v.w;
    __syncthreads();
    ushort4 uv;
    uv.x = f2bu(tile[j4 + 0][r]);
    uv.y = f2bu(tile[j4 + 1][r]);
    uv.z = f2bu(tile[j4 + 2][r]);
    uv.w = f2bu(tile[j4 + 3][r]);
    *(ushort4*)(xt + ((size_t)(n * HWD + q0 + r)) * CC + c0 + j4) = uv;
}

// ---------------- embed GEMM: tp = xt * Wcat^T + bias ----------------
__global__ __launch_bounds__(256) void k_embed(const unsigned short* __restrict__ xt,
                                               const unsigned short* __restrict__ Wcat,
                                               const float* __restrict__ bt,
                                               const float* __restrict__ bp,
                                               unsigned short* __restrict__ tp) {
    __shared__ __align__(16) unsigned short As[128 * 40];
    __shared__ __align__(16) unsigned short Bs[128 * 40];
    const int m0 = blockIdx.x << 7, n0 = blockIdx.y << 7;
    const int t = threadIdx.x, lane = t & 63, wave = t >> 6;
    const int wr = wave >> 1, wc = wave & 1;
    const int lrow = lane & 15, hi = lane >> 4, lhk = hi << 3;
    const f32x4 fz = {0.f, 0.f, 0.f, 0.f};
    f32x4 acc[4][4];
#pragma unroll
    for (int i = 0; i < 4; ++i)
#pragma unroll
        for (int j = 0; j < 4; ++j) acc[i][j] = fz;

    for (int kt = 0; kt < 16; ++kt) {
        const int k0 = kt << 5;
#pragma unroll
        for (int i = 0; i < 2; ++i) {
            int chunk = t + (i << 8);
            int r = chunk >> 2, ko = (chunk & 3) << 3;
            *(uint4*)(As + r * 40 + ko) =
                *(const uint4*)(xt + ((size_t)(m0 + r)) * CC + k0 + ko);
            *(uint4*)(Bs + r * 40 + ko) =
                *(const uint4*)(Wcat + ((size_t)(n0 + r)) * CC + k0 + ko);
        }
        __syncthreads();
        short8 af[4], bfm[4];
#pragma unroll
        for (int mi = 0; mi < 4; ++mi)
            af[mi] = *(const short8*)(As + (wr * 64 + mi * 16 + lrow) * 40 + lhk);
#pragma unroll
        for (int ni = 0; ni < 4; ++ni)
            bfm[ni] = *(const short8*)(Bs + (wc * 64 + ni * 16 + lrow) * 40 + lhk);
#pragma unroll
        for (int mi = 0; mi < 4; ++mi)
#pragma unroll
            for (int ni = 0; ni < 4; ++ni)
                acc[mi][ni] = __builtin_amdgcn_mfma_f32_16x16x32_bf16(
                    af[mi], bfm[ni], acc[mi][ni], 0, 0, 0);
        __syncthreads();
    }
#pragma unroll
    for (int ni = 0; ni < 4; ++ni) {
        const int col = n0 + wc * 64 + ni * 16 + lrow;
        const float bias = (col < 256) ? bt[col] : bp[col - 256];
#pragma unroll
        for (int mi = 0; mi < 4; ++mi)
#pragma unroll
            for (int j = 0; j < 4; ++j) {
                const int row = m0 + wr * 64 + mi * 16 + hi * 4 + j;
                tp[(size_t)row * CC + col] = f2bu(acc[mi][ni][j] + bias);
            }
    }
}

// ---------------- attention ----------------
__global__ __launch_bounds__(256) void k_attn(const unsigned short* __restrict__ tp,
                                              const float* __restrict__ x,
                                              unsigned short* __restrict__ at) {
    constexpr int PST = 1032;                      // padded row stride (bf16 elems)
    __shared__ __align__(16) unsigned short P[32 * PST];
    __shared__ float rowsum[32];
    const int n = blockIdx.y, q0 = blockIdx.x << 5;
    const int t = threadIdx.x, lane = t & 63, wave = t >> 6;
    const int lrow = lane & 15, hi = lane >> 4, lhk = hi << 3;
    const f32x4 fz = {0.f, 0.f, 0.f, 0.f};
    if (t < 32) rowsum[t] = 0.f;
    __syncthreads();

    const unsigned short* tpn = tp + (size_t)n * HWD * CC;
    float psum[2][4] = {{0.f, 0.f, 0.f, 0.f}, {0.f, 0.f, 0.f, 0.f}};
    const int kbase = wave << 8;                   // this wave's 256-key range

    // Phase A: S = Q K^T / 16, P = exp(S)
    for (int ni = 0; ni < 16; ++ni) {
        f32x4 accA[2];
        accA[0] = fz; accA[1] = fz;
        const int kk = kbase + (ni << 4);
#pragma unroll
        for (int kt = 0; kt < 8; ++kt) {
            const int d0 = (kt << 5) + lhk;
            short8 bfr = *(const short8*)(tpn + (size_t)(kk + lrow) * CC + 256 + d0);
            short8 a0  = *(const short8*)(tpn + (size_t)(q0 + lrow) * CC + d0);
            short8 a1  = *(const short8*)(tpn + (size_t)(q0 + 16 + lrow) * CC + d0);
            accA[0] = __builtin_amdgcn_mfma_f32_16x16x32_bf16(a0, bfr, accA[0], 0, 0, 0);
            accA[1] = __builtin_amdgcn_mfma_f32_16x16x32_bf16(a1, bfr, accA[1], 0, 0, 0);
        }
#pragma unroll
        for (int qi = 0; qi < 2; ++qi)
#pragma unroll
            for (int j = 0; j < 4; ++j) {
                float p = __expf(accA[qi][j] * 0.0625f);
                psum[qi][j] += p;
                P[(qi * 16 + hi * 4 + j) * PST + kk + lrow] = f2bu(p);
            }
    }
    // row sums: reduce over 16 key-columns, then across the 4 waves via LDS atomics
#pragma unroll
    for (int qi = 0; qi < 2; ++qi)
#pragma unroll
        for (int j = 0; j < 4; ++j) {
            float s = psum[qi][j];
            s += __shfl_xor(s, 1, 16);
            s += __shfl_xor(s, 2, 16);
            s += __shfl_xor(s, 4, 16);
            s += __shfl_xor(s, 8, 16);
            if (lrow == 0) atomicAdd(&rowsum[qi * 16 + hi * 4 + j], s);
        }
    __syncthreads();

    // Phase B: O = P V^T, V = x[n,c,k] (fp32 -> bf16 on the fly)
    f32x4 accO[2][8];
#pragma unroll
    for (int ci = 0; ci < 8; ++ci) { accO[0][ci] = fz; accO[1][ci] = fz; }
    const float* xn = x + (size_t)n * CC * HWD;
    const int c0 = wave << 7;                      // this wave's 128-channel range
    for (int ks = 0; ks < 32; ++ks) {
        const int kb = (ks << 5) + lhk;
        short8 a0 = *(const short8*)(P + lrow * PST + kb);
        short8 a1 = *(const short8*)(P + (16 + lrow) * PST + kb);
#pragma unroll
        for (int ci = 0; ci < 8; ++ci) {
            const int c = c0 + (ci << 4) + lrow;
            const float4 v0 = *(const float4*)(xn + (size_t)c * HWD + kb);
            const float4 v1 = *(const float4*)(xn + (size_t)c * HWD + kb + 4);
            short8 bfr;
            bfr[0] = (short)f2bu(v0.x); bfr[1] = (short)f2bu(v0.y);
            bfr[2] = (short)f2bu(v0.z); bfr[3] = (short)f2bu(v0.w);
            bfr[4] = (short)f2bu(v1.x); bfr[5] = (short)f2bu(v1.y);
            bfr[6] = (short)f2bu(v1.z); bfr[7] = (short)f2bu(v1.w);
            accO[0][ci] = __builtin_amdgcn_mfma_f32_16x16x32_bf16(a0, bfr, accO[0][ci], 0, 0, 0);
            accO[1][ci] = __builtin_amdgcn_mfma_f32_16x16x32_bf16(a1, bfr, accO[1][ci], 0, 0, 0);
        }
    }
    float inv[2][4];
#pragma unroll
    for (int qi = 0; qi < 2; ++qi)
#pragma unroll
        for (int j = 0; j < 4; ++j)
            inv[qi][j] = 1.f / rowsum[qi * 16 + hi * 4 + j];
    unsigned short* atn = at + ((size_t)(n * HWD + q0)) * CC;
#pragma unroll
    for (int ci = 0; ci < 8; ++ci) {
        const int c = c0 + (ci << 4) + lrow;
#pragma unroll
        for (int qi = 0; qi < 2; ++qi)
#pragma unroll
            for (int j = 0; j < 4; ++j) {
                const int row = qi * 16 + hi * 4 + j;
                atn[(size_t)row * CC + c] = f2bu(accO[qi][ci][j] * inv[qi][j]);
            }
    }
}

// ---------------- fuse GEMM + residual: out[n,o,q] ----------------
__global__ __launch_bounds__(256) void k_fuse(const unsigned short* __restrict__ Wfuse,
                                              const unsigned short* __restrict__ at,
                                              const float* __restrict__ bfu,
                                              const float* __restrict__ x,
                                              float* __restrict__ out) {
    __shared__ __align__(16) unsigned short As[128 * 40];
    __shared__ __align__(16) unsigned short Bs[128 * 40];
    const int q0 = blockIdx.x << 7, o0 = blockIdx.y << 7, n = blockIdx.z;
    const int t = threadIdx.x, lane = t & 63, wave = t >> 6;
    const int wr = wave >> 1, wc = wave & 1;
    const int lrow = lane & 15, hi = lane >> 4, lhk = hi << 3;
    const f32x4 fz = {0.f, 0.f, 0.f, 0.f};
    f32x4 acc[4][4];
#pragma unroll
    for (int i = 0; i < 4; ++i)
#pragma unroll
        for (int j = 0; j < 4; ++j) acc[i][j] = fz;

    const unsigned short* atn = at + ((size_t)(n * HWD + q0)) * CC;
    for (int kt = 0; kt < 16; ++kt) {
        const int k0 = kt << 5;
#pragma unroll
        for (int i = 0; i < 2; ++i) {
            int chunk = t + (i << 8);
            int r = chunk >> 2, ko = (chunk & 3) << 3;
            *(uint4*)(As + r * 40 + ko) =
                *(const uint4*)(Wfuse + ((size_t)(o0 + r)) * CC + k0 + ko);
            *(uint4*)(Bs + r * 40 + ko) =
                *(const uint4*)(atn + (size_t)r * CC + k0 + ko);
        }
        __syncthreads();
        short8 af[4], bfm[4];
#pragma unroll
        for (int mi = 0; mi < 4; ++mi)
            af[mi] = *(const short8*)(As + (wr * 64 + mi * 16 + lrow) * 40 + lhk);
#pragma unroll
        for (int ni = 0; ni < 4; ++ni)
            bfm[ni] = *(const short8*)(Bs + (wc * 64 + ni * 16 + lrow) * 40 + lhk);
#pragma unroll
        for (int mi = 0; mi < 4; ++mi)
#pragma unroll
            for (int ni = 0; ni < 4; ++ni)
                acc[mi][ni] = __builtin_amdgcn_mfma_f32_16x16x32_bf16(
                    af[mi], bfm[ni], acc[mi][ni], 0, 0, 0);
        __syncthreads();
    }
#pragma unroll
    for (int ni = 0; ni < 4; ++ni) {
        const int q = q0 + wc * 64 + ni * 16 + lrow;
#pragma unroll
        for (int mi = 0; mi < 4; ++mi)
#pragma unroll
            for (int j = 0; j < 4; ++j) {
                const int o = o0 + wr * 64 + mi * 16 + hi * 4 + j;
                const size_t idx = ((size_t)(n * CC + o)) * HWD + q;
                out[idx] = acc[mi][ni][j] + bfu[o] + x[idx];
            }
    }
}

extern "C" void kernel_launch(void* const* d_in, const int* in_sizes, int n_in,
                              void* d_out, int out_size, void* d_ws, size_t ws_size,
                              hipStream_t stream) {
    const float* x  = (const float*)d_in[0];
    const float* Wt = (const float*)d_in[1];
    const float* bt = (const float*)d_in[2];
    const float* Wp = (const float*)d_in[3];
    const float* bp = (const float*)d_in[4];
    const float* Wf = (const float*)d_in[5];
    const float* bfu = (const float*)d_in[6];
    float* out = (float*)d_out;

    char* ws = (char*)d_ws;
    unsigned short* xt_at = (unsigned short*)(ws);                 // 32 MB (xt, later at)
    unsigned short* tp    = (unsigned short*)(ws + 33554432);      // 32 MB
    unsigned short* Wcat  = (unsigned short*)(ws + 67108864);      // 512 KB
    unsigned short* Wfuse = (unsigned short*)(ws + 67633152);      // 512 KB

    k_packw<<<dim3(1024), 256, 0, stream>>>(Wt, Wp, Wf, Wcat, Wfuse);
    k_prep <<<dim3(32, 16, 32), 256, 0, stream>>>(x, xt_at);
    k_embed<<<dim3(256, 4), 256, 0, stream>>>(xt_at, Wcat, bt, bp, tp);
    k_attn <<<dim3(32, 32), 256, 0, stream>>>(tp, x, xt_at);       // at overwrites xt
    k_fuse <<<dim3(8, 4, 32), 256, 0, stream>>>(Wfuse, xt_at, bfu, x, out);
}

// Round 2
// 324.892 us; speedup vs baseline: 1.2728x; 1.2728x over previous
//
#include <hip/hip_runtime.h>

// Problem: N=32, C=512, H=W=32 (HW=1024), D=256.
// out = x + W_fuse * softmax((Wt x)^T (Wp x) / 16) applied to values x, per batch.
//
// Pipeline (all bf16 MFMA, fp32 accumulate):
//  k_packw : W_theta|W_phi -> Wcat bf16 [512][512], W_fuse -> bf16 [512][512]
//  k_prep  : x [n,c,q] fp32 -> xt [n,q,c] bf16 (transposed, pixel-major)
//  k_embed : tp[n,q,0:256]=theta, [256:512]=phi  (GEMM 32768x512x512)
//  k_cast  : x fp32 -> xb bf16 [n,c,q] (native layout), overwrites xt space
//  k_attn2 : per (n, 32-query tile): S=Q K^T/16 (Q frags in regs), P=exp(S) in
//            LDS, rowsums, O = P V^T / rowsum (V=xb, direct bf16 loads),
//            then fused: out[n,o,q] = x + b_fuse[o] + W_fuse . O   (fp32 out)
//
// Workspace (65 MB):
//   [0,32MB)    xt  (k_prep->k_embed), then xb (k_cast->k_attn2)
//   [32,64MB)   tp
//   [64MB,+512K)  Wcat bf16 ; [+512K,+1MB) Wfuse bf16

#define NB  32
#define CC  512
#define HWD 1024

typedef __attribute__((ext_vector_type(8))) short short8;
typedef __attribute__((ext_vector_type(4))) float f32x4;

__device__ __forceinline__ unsigned short f2bu(float f) {
    unsigned int u = __float_as_uint(f);
    u = (u + 0x7FFFu + ((u >> 16) & 1u)) >> 16;   // RNE to bf16
    return (unsigned short)u;
}

// ---------------- weights pack ----------------
__global__ __launch_bounds__(256) void k_packw(const float* __restrict__ Wt,
                                               const float* __restrict__ Wp,
                                               const float* __restrict__ Wf,
                                               unsigned short* __restrict__ Wcat,
                                               unsigned short* __restrict__ Wfuse) {
    int idx = blockIdx.x * 256 + threadIdx.x;       // 0 .. 262143
    int o = idx >> 9;
    float cv = (o < 256) ? Wt[idx] : Wp[idx - 131072];
    Wcat[idx]  = f2bu(cv);
    Wfuse[idx] = f2bu(Wf[idx]);
}

// ---------------- x transpose -> xt[n,q,c] bf16 ----------------
__global__ __launch_bounds__(256) void k_prep(const float* __restrict__ x,
                                              unsigned short* __restrict__ xt) {
    __shared__ float tile[32][33];
    const int n = blockIdx.z, c0 = blockIdx.y << 5, q0 = blockIdx.x << 5;
    const int t = threadIdx.x;
    const int r = t >> 3, j4 = (t & 7) << 2;
    const float* src = x + ((size_t)(n * CC + c0 + r)) * HWD + q0 + j4;
    float4 v = *(const float4*)src;
    tile[r][j4 + 0] = v.x; tile[r][j4 + 1] = v.y;
    tile[r][j4 + 2] = v.z; tile[r][j4 + 3] = v.w;
    __syncthreads();
    ushort4 uv;
    uv.x = f2bu(tile[j4 + 0][r]);
    uv.y = f2bu(tile[j4 + 1][r]);
    uv.z = f2bu(tile[j4 + 2][r]);
    uv.w = f2bu(tile[j4 + 3][r]);
    *(ushort4*)(xt + ((size_t)(n * HWD + q0 + r)) * CC + c0 + j4) = uv;
}

// ---------------- x -> xb bf16 (same layout) ----------------
__global__ __launch_bounds__(256) void k_cast(const float* __restrict__ x,
                                              unsigned short* __restrict__ xb) {
    const size_t i = ((size_t)blockIdx.x * 256 + threadIdx.x) * 8;
    float4 v0 = *(const float4*)(x + i);
    float4 v1 = *(const float4*)(x + i + 4);
    short8 o;
    o[0] = (short)f2bu(v0.x); o[1] = (short)f2bu(v0.y);
    o[2] = (short)f2bu(v0.z); o[3] = (short)f2bu(v0.w);
    o[4] = (short)f2bu(v1.x); o[5] = (short)f2bu(v1.y);
    o[6] = (short)f2bu(v1.z); o[7] = (short)f2bu(v1.w);
    *(short8*)(xb + i) = o;
}

// ---------------- embed GEMM: tp = xt * Wcat^T + bias ----------------
__global__ __launch_bounds__(256) void k_embed(const unsigned short* __restrict__ xt,
                                               const unsigned short* __restrict__ Wcat,
                                               const float* __restrict__ bt,
                                               const float* __restrict__ bp,
                                               unsigned short* __restrict__ tp) {
    __shared__ __align__(16) unsigned short As[128 * 40];
    __shared__ __align__(16) unsigned short Bs[128 * 40];
    const int m0 = blockIdx.x << 7, n0 = blockIdx.y << 7;
    const int t = threadIdx.x, lane = t & 63, wave = t >> 6;
    const int wr = wave >> 1, wc = wave & 1;
    const int lrow = lane & 15, hi = lane >> 4, lhk = hi << 3;
    const f32x4 fz = {0.f, 0.f, 0.f, 0.f};
    f32x4 acc[4][4];
#pragma unroll
    for (int i = 0; i < 4; ++i)
#pragma unroll
        for (int j = 0; j < 4; ++j) acc[i][j] = fz;

    for (int kt = 0; kt < 16; ++kt) {
        const int k0 = kt << 5;
#pragma unroll
        for (int i = 0; i < 2; ++i) {
            int chunk = t + (i << 8);
            int r = chunk >> 2, ko = (chunk & 3) << 3;
            *(uint4*)(As + r * 40 + ko) =
                *(const uint4*)(xt + ((size_t)(m0 + r)) * CC + k0 + ko);
            *(uint4*)(Bs + r * 40 + ko) =
                *(const uint4*)(Wcat + ((size_t)(n0 + r)) * CC + k0 + ko);
        }
        __syncthreads();
        short8 af[4], bfm[4];
#pragma unroll
        for (int mi = 0; mi < 4; ++mi)
            af[mi] = *(const short8*)(As + (wr * 64 + mi * 16 + lrow) * 40 + lhk);
#pragma unroll
        for (int ni = 0; ni < 4; ++ni)
            bfm[ni] = *(const short8*)(Bs + (wc * 64 + ni * 16 + lrow) * 40 + lhk);
#pragma unroll
        for (int mi = 0; mi < 4; ++mi)
#pragma unroll
            for (int ni = 0; ni < 4; ++ni)
                acc[mi][ni] = __builtin_amdgcn_mfma_f32_16x16x32_bf16(
                    af[mi], bfm[ni], acc[mi][ni], 0, 0, 0);
        __syncthreads();
    }
#pragma unroll
    for (int ni = 0; ni < 4; ++ni) {
        const int col = n0 + wc * 64 + ni * 16 + lrow;
        const float bias = (col < 256) ? bt[col] : bp[col - 256];
#pragma unroll
        for (int mi = 0; mi < 4; ++mi)
#pragma unroll
            for (int j = 0; j < 4; ++j) {
                const int row = m0 + wr * 64 + mi * 16 + hi * 4 + j;
                tp[(size_t)row * CC + col] = f2bu(acc[mi][ni][j] + bias);
            }
    }
}

// ---------------- fused attention + fuse conv + residual ----------------
__global__ __launch_bounds__(256) void k_attn2(const unsigned short* __restrict__ tp,
                                               const unsigned short* __restrict__ xb,
                                               const unsigned short* __restrict__ Wfuse,
                                               const float* __restrict__ bfu,
                                               const float* __restrict__ x,
                                               float* __restrict__ out) {
    constexpr int PST = 1032;                      // padded P row stride (bf16)
    constexpr int OST = 520;                       // padded O row stride (bf16)
    __shared__ __align__(16) unsigned short P[32 * PST];   // 64.5 KB; Os overlays
    __shared__ float rowsum[32];
    const int n = blockIdx.y, q0 = blockIdx.x << 5;
    const int t = threadIdx.x, lane = t & 63, wave = t >> 6;
    const int lrow = lane & 15, hi = lane >> 4, lhk = hi << 3;
    const f32x4 fz = {0.f, 0.f, 0.f, 0.f};
    if (t < 32) rowsum[t] = 0.f;

    const unsigned short* tpn = tp + (size_t)n * HWD * CC;

    // preload Q fragments (rows q0..q0+31, all of d=256)
    short8 qf[2][8];
#pragma unroll
    for (int qi = 0; qi < 2; ++qi)
#pragma unroll
        for (int kt = 0; kt < 8; ++kt)
            qf[qi][kt] = *(const short8*)(tpn + (size_t)(q0 + qi * 16 + lrow) * CC +
                                          (kt << 5) + lhk);
    __syncthreads();

    float psum[2][4] = {{0.f, 0.f, 0.f, 0.f}, {0.f, 0.f, 0.f, 0.f}};
    const int kbase = wave << 8;                   // this wave's 256-key range

    // Phase A: S = Q K^T / 16, P = exp(S)
    for (int ni = 0; ni < 16; ++ni) {
        f32x4 accA[2];
        accA[0] = fz; accA[1] = fz;
        const int kk = kbase + (ni << 4);
#pragma unroll
        for (int kt = 0; kt < 8; ++kt) {
            short8 bfr = *(const short8*)(tpn + (size_t)(kk + lrow) * CC + 256 +
                                          (kt << 5) + lhk);
            accA[0] = __builtin_amdgcn_mfma_f32_16x16x32_bf16(qf[0][kt], bfr, accA[0], 0, 0, 0);
            accA[1] = __builtin_amdgcn_mfma_f32_16x16x32_bf16(qf[1][kt], bfr, accA[1], 0, 0, 0);
        }
#pragma unroll
        for (int qi = 0; qi < 2; ++qi)
#pragma unroll
            for (int j = 0; j < 4; ++j) {
                float p = __expf(accA[qi][j] * 0.0625f);
                psum[qi][j] += p;
                P[(qi * 16 + hi * 4 + j) * PST + kk + lrow] = f2bu(p);
            }
    }
#pragma unroll
    for (int qi = 0; qi < 2; ++qi)
#pragma unroll
        for (int j = 0; j < 4; ++j) {
            float s = psum[qi][j];
            s += __shfl_xor(s, 1, 16);
            s += __shfl_xor(s, 2, 16);
            s += __shfl_xor(s, 4, 16);
            s += __shfl_xor(s, 8, 16);
            if (lrow == 0) atomicAdd(&rowsum[qi * 16 + hi * 4 + j], s);
        }
    __syncthreads();

    // Phase B: O = P V^T, V = xb[n,c,k] bf16 (direct loads)
    f32x4 accO[2][8];
#pragma unroll
    for (int ci = 0; ci < 8; ++ci) { accO[0][ci] = fz; accO[1][ci] = fz; }
    const unsigned short* xbn = xb + (size_t)n * CC * HWD;
    const int c0 = wave << 7;                      // this wave's 128-channel range
    for (int ks = 0; ks < 32; ++ks) {
        const int kb = (ks << 5) + lhk;
        short8 a0 = *(const short8*)(P + lrow * PST + kb);
        short8 a1 = *(const short8*)(P + (16 + lrow) * PST + kb);
#pragma unroll
        for (int ci = 0; ci < 8; ++ci) {
            const int c = c0 + (ci << 4) + lrow;
            short8 bfr = *(const short8*)(xbn + (size_t)c * HWD + kb);
            accO[0][ci] = __builtin_amdgcn_mfma_f32_16x16x32_bf16(a0, bfr, accO[0][ci], 0, 0, 0);
            accO[1][ci] = __builtin_amdgcn_mfma_f32_16x16x32_bf16(a1, bfr, accO[1][ci], 0, 0, 0);
        }
    }
    float inv[2][4];
#pragma unroll
    for (int qi = 0; qi < 2; ++qi)
#pragma unroll
        for (int j = 0; j < 4; ++j)
            inv[qi][j] = 1.f / rowsum[qi * 16 + hi * 4 + j];

    __syncthreads();                               // all waves done reading P
    unsigned short* Os = P;                        // overlay: O tile [32][OST]
#pragma unroll
    for (int ci = 0; ci < 8; ++ci) {
        const int c = c0 + (ci << 4) + lrow;
#pragma unroll
        for (int qi = 0; qi < 2; ++qi)
#pragma unroll
            for (int j = 0; j < 4; ++j)
                Os[(qi * 16 + hi * 4 + j) * OST + c] = f2bu(accO[qi][ci][j] * inv[qi][j]);
    }
    __syncthreads();

    // Phase C: out[n, o, q0..q0+32) = x + b_fuse[o] + W_fuse . O
    f32x4 accF[8][2];
#pragma unroll
    for (int mi = 0; mi < 8; ++mi) { accF[mi][0] = fz; accF[mi][1] = fz; }
    const int ob = wave << 7;                      // this wave's 128-output range
    for (int kt = 0; kt < 16; ++kt) {
        const int k0 = (kt << 5) + lhk;
        short8 bq0 = *(const short8*)(Os + lrow * OST + k0);
        short8 bq1 = *(const short8*)(Os + (16 + lrow) * OST + k0);
#pragma unroll
        for (int mi = 0; mi < 8; ++mi) {
            short8 af = *(const short8*)(Wfuse + (size_t)(ob + (mi << 4) + lrow) * CC + k0);
            accF[mi][0] = __builtin_amdgcn_mfma_f32_16x16x32_bf16(af, bq0, accF[mi][0], 0, 0, 0);
            accF[mi][1] = __builtin_amdgcn_mfma_f32_16x16x32_bf16(af, bq1, accF[mi][1], 0, 0, 0);
        }
    }
#pragma unroll
    for (int mi = 0; mi < 8; ++mi) {
        const int o = ob + (mi << 4) + hi * 4;
#pragma unroll
        for (int j = 0; j < 4; ++j) {
            const float bias = bfu[o + j];
#pragma unroll
            for (int nj = 0; nj < 2; ++nj) {
                const int q = q0 + nj * 16 + lrow;
                const size_t idx = ((size_t)(n * CC + o + j)) * HWD + q;
                out[idx] = accF[mi][nj][j] + bias + x[idx];
            }
        }
    }
}

extern "C" void kernel_launch(void* const* d_in, const int* in_sizes, int n_in,
                              void* d_out, int out_size, void* d_ws, size_t ws_size,
                              hipStream_t stream) {
    const float* x  = (const float*)d_in[0];
    const float* Wt = (const float*)d_in[1];
    const float* bt = (const float*)d_in[2];
    const float* Wp = (const float*)d_in[3];
    const float* bp = (const float*)d_in[4];
    const float* Wf = (const float*)d_in[5];
    const float* bfu = (const float*)d_in[6];
    float* out = (float*)d_out;

    char* ws = (char*)d_ws;
    unsigned short* xt_xb = (unsigned short*)(ws);                 // 32 MB (xt, later xb)
    unsigned short* tp    = (unsigned short*)(ws + 33554432);      // 32 MB
    unsigned short* Wcat  = (unsigned short*)(ws + 67108864);      // 512 KB
    unsigned short* Wfuse = (unsigned short*)(ws + 67633152);      // 512 KB

    k_packw<<<dim3(1024), 256, 0, stream>>>(Wt, Wp, Wf, Wcat, Wfuse);
    k_prep <<<dim3(32, 16, 32), 256, 0, stream>>>(x, xt_xb);
    k_embed<<<dim3(256, 4), 256, 0, stream>>>(xt_xb, Wcat, bt, bp, tp);
    k_cast <<<dim3(8192), 256, 0, stream>>>(x, xt_xb);             // xb overwrites xt
    k_attn2<<<dim3(32, 32), 256, 0, stream>>>(tp, xt_xb, Wfuse, bfu, x, out);
}

// Round 3
// 246.092 us; speedup vs baseline: 1.6803x; 1.3202x over previous
//
#include <hip/hip_runtime.h>

// Problem: N=32, C=512, H=W=32 (HW=1024), D=256.
// out = x + W_fuse * softmax((Wt x)^T (Wp x) / 16) applied to values x, per batch.
//
// Pipeline (all bf16 MFMA, fp32 accumulate):
//  k_packw : W_theta|W_phi -> Wcat bf16 [512][512], W_fuse -> bf16 [512][512]
//  k_prep  : x [n,c,q] fp32 -> xt [n,q,c] bf16 (transposed, pixel-major)
//  k_embed : tp[n,q,0:256]=theta, [256:512]=phi  (GEMM 32768x512x512)
//  k_cast  : x fp32 -> xb bf16 [n,c,q] (native layout), overwrites xt space
//  k_attn3 : flash-style per (n, 64-query tile), 8 waves:
//            loop 8 KV-tiles of 128 keys: S=Q K^T/16 (Q in LDS, K from L2),
//            P=exp(S) -> LDS [64][136], PV accumulate in regs (V=xb bf16).
//            Then rowsum-normalize -> Os LDS [64][520] -> fused 1x1 conv
//            out[n,o,q] = x + b_fuse[o] + W_fuse . O  (fp32 out)
//
// Workspace (65 MB):
//   [0,32MB)    xt  (k_prep->k_embed), then xb (k_cast->k_attn3)
//   [32,64MB)   tp
//   [64MB,+512K)  Wcat bf16 ; [+512K,+1MB) Wfuse bf16

#define NB  32
#define CC  512
#define HWD 1024

typedef __attribute__((ext_vector_type(8))) short short8;
typedef __attribute__((ext_vector_type(4))) float f32x4;

__device__ __forceinline__ unsigned short f2bu(float f) {
    unsigned int u = __float_as_uint(f);
    u = (u + 0x7FFFu + ((u >> 16) & 1u)) >> 16;   // RNE to bf16
    return (unsigned short)u;
}

// ---------------- weights pack ----------------
__global__ __launch_bounds__(256) void k_packw(const float* __restrict__ Wt,
                                               const float* __restrict__ Wp,
                                               const float* __restrict__ Wf,
                                               unsigned short* __restrict__ Wcat,
                                               unsigned short* __restrict__ Wfuse) {
    int idx = blockIdx.x * 256 + threadIdx.x;       // 0 .. 262143
    int o = idx >> 9;
    float cv = (o < 256) ? Wt[idx] : Wp[idx - 131072];
    Wcat[idx]  = f2bu(cv);
    Wfuse[idx] = f2bu(Wf[idx]);
}

// ---------------- x transpose -> xt[n,q,c] bf16 ----------------
__global__ __launch_bounds__(256) void k_prep(const float* __restrict__ x,
                                              unsigned short* __restrict__ xt) {
    __shared__ float tile[32][33];
    const int n = blockIdx.z, c0 = blockIdx.y << 5, q0 = blockIdx.x << 5;
    const int t = threadIdx.x;
    const int r = t >> 3, j4 = (t & 7) << 2;
    const float* src = x + ((size_t)(n * CC + c0 + r)) * HWD + q0 + j4;
    float4 v = *(const float4*)src;
    tile[r][j4 + 0] = v.x; tile[r][j4 + 1] = v.y;
    tile[r][j4 + 2] = v.z; tile[r][j4 + 3] = v.w;
    __syncthreads();
    ushort4 uv;
    uv.x = f2bu(tile[j4 + 0][r]);
    uv.y = f2bu(tile[j4 + 1][r]);
    uv.z = f2bu(tile[j4 + 2][r]);
    uv.w = f2bu(tile[j4 + 3][r]);
    *(ushort4*)(xt + ((size_t)(n * HWD + q0 + r)) * CC + c0 + j4) = uv;
}

// ---------------- x -> xb bf16 (same layout) ----------------
__global__ __launch_bounds__(256) void k_cast(const float* __restrict__ x,
                                              unsigned short* __restrict__ xb) {
    const size_t i = ((size_t)blockIdx.x * 256 + threadIdx.x) * 8;
    float4 v0 = *(const float4*)(x + i);
    float4 v1 = *(const float4*)(x + i + 4);
    short8 o;
    o[0] = (short)f2bu(v0.x); o[1] = (short)f2bu(v0.y);
    o[2] = (short)f2bu(v0.z); o[3] = (short)f2bu(v0.w);
    o[4] = (short)f2bu(v1.x); o[5] = (short)f2bu(v1.y);
    o[6] = (short)f2bu(v1.z); o[7] = (short)f2bu(v1.w);
    *(short8*)(xb + i) = o;
}

// ---------------- embed GEMM: tp = xt * Wcat^T + bias ----------------
__global__ __launch_bounds__(256) void k_embed(const unsigned short* __restrict__ xt,
                                               const unsigned short* __restrict__ Wcat,
                                               const float* __restrict__ bt,
                                               const float* __restrict__ bp,
                                               unsigned short* __restrict__ tp) {
    __shared__ __align__(16) unsigned short As[128 * 40];
    __shared__ __align__(16) unsigned short Bs[128 * 40];
    const int m0 = blockIdx.x << 7, n0 = blockIdx.y << 7;
    const int t = threadIdx.x, lane = t & 63, wave = t >> 6;
    const int wr = wave >> 1, wc = wave & 1;
    const int lrow = lane & 15, hi = lane >> 4, lhk = hi << 3;
    const f32x4 fz = {0.f, 0.f, 0.f, 0.f};
    f32x4 acc[4][4];
#pragma unroll
    for (int i = 0; i < 4; ++i)
#pragma unroll
        for (int j = 0; j < 4; ++j) acc[i][j] = fz;

    for (int kt = 0; kt < 16; ++kt) {
        const int k0 = kt << 5;
#pragma unroll
        for (int i = 0; i < 2; ++i) {
            int chunk = t + (i << 8);
            int r = chunk >> 2, ko = (chunk & 3) << 3;
            *(uint4*)(As + r * 40 + ko) =
                *(const uint4*)(xt + ((size_t)(m0 + r)) * CC + k0 + ko);
            *(uint4*)(Bs + r * 40 + ko) =
                *(const uint4*)(Wcat + ((size_t)(n0 + r)) * CC + k0 + ko);
        }
        __syncthreads();
        short8 af[4], bfm[4];
#pragma unroll
        for (int mi = 0; mi < 4; ++mi)
            af[mi] = *(const short8*)(As + (wr * 64 + mi * 16 + lrow) * 40 + lhk);
#pragma unroll
        for (int ni = 0; ni < 4; ++ni)
            bfm[ni] = *(const short8*)(Bs + (wc * 64 + ni * 16 + lrow) * 40 + lhk);
#pragma unroll
        for (int mi = 0; mi < 4; ++mi)
#pragma unroll
            for (int ni = 0; ni < 4; ++ni)
                acc[mi][ni] = __builtin_amdgcn_mfma_f32_16x16x32_bf16(
                    af[mi], bfm[ni], acc[mi][ni], 0, 0, 0);
        __syncthreads();
    }
#pragma unroll
    for (int ni = 0; ni < 4; ++ni) {
        const int col = n0 + wc * 64 + ni * 16 + lrow;
        const float bias = (col < 256) ? bt[col] : bp[col - 256];
#pragma unroll
        for (int mi = 0; mi < 4; ++mi)
#pragma unroll
            for (int j = 0; j < 4; ++j) {
                const int row = m0 + wr * 64 + mi * 16 + hi * 4 + j;
                tp[(size_t)row * CC + col] = f2bu(acc[mi][ni][j] + bias);
            }
    }
}

// ---------------- flash attention + fuse conv + residual ----------------
// 8 waves, 64-query tile, KV tiles of 128 keys.
// LDS union: [ Q(64x264) | P(64x136) ]  overlaid later by Os(64x520).
__global__ __launch_bounds__(512, 4) void k_attn3(const unsigned short* __restrict__ tp,
                                                  const unsigned short* __restrict__ xb,
                                                  const unsigned short* __restrict__ Wfuse,
                                                  const float* __restrict__ bfu,
                                                  const float* __restrict__ x,
                                                  float* __restrict__ out) {
    constexpr int QST = 264;                       // Q row stride (bf16)
    constexpr int PST = 136;                       // P row stride (bf16)
    constexpr int OST = 520;                       // Os row stride (bf16)
    __shared__ __align__(16) unsigned short SL[64 * OST];   // 66,560 B
    __shared__ float rowsum[64];
    unsigned short* Qs = SL;                       // [64][264]
    unsigned short* P  = SL + 64 * QST;            // [64][136]
    unsigned short* Os = SL;                       // overlay [64][520]

    const int n = blockIdx.y, q0 = blockIdx.x << 6;
    const int t = threadIdx.x, lane = t & 63, wave = t >> 6;
    const int lrow = lane & 15, hi = lane >> 4, lhk = hi << 3;
    const f32x4 fz = {0.f, 0.f, 0.f, 0.f};

    const unsigned short* tpn = tp + (size_t)n * HWD * CC;
    const unsigned short* xbn = xb + (size_t)n * CC * HWD;

    if (t < 64) rowsum[t] = 0.f;
    // stage Q tile: rows q0..q0+63, d 0..255
#pragma unroll
    for (int pass = 0; pass < 4; ++pass) {
        int chunk = (pass << 9) + t;               // 0..2047
        int row = chunk >> 5, co = (chunk & 31) << 3;
        *(short8*)(Qs + row * QST + co) =
            *(const short8*)(tpn + (size_t)(q0 + row) * CC + co);
    }
    __syncthreads();

    f32x4 accO[4][4];
#pragma unroll
    for (int qj = 0; qj < 4; ++qj)
#pragma unroll
        for (int ci = 0; ci < 4; ++ci) accO[qj][ci] = fz;
    float psum[4][4];
#pragma unroll
    for (int qj = 0; qj < 4; ++qj)
#pragma unroll
        for (int j = 0; j < 4; ++j) psum[qj][j] = 0.f;

    const int kw = wave << 4;                      // wave's 16-key slot in tile
    const int cw = wave << 6;                      // wave's 64-channel range

    for (int it = 0; it < 8; ++it) {
        const int kv0 = it << 7;                   // KV tile base (128 keys)
        // ---- S = Q K^T / 16, P = exp(S) ----
        f32x4 accA[4];
#pragma unroll
        for (int qj = 0; qj < 4; ++qj) accA[qj] = fz;
#pragma unroll
        for (int kt = 0; kt < 8; ++kt) {
            const int d0 = (kt << 5) + lhk;
            short8 kfr = *(const short8*)(tpn + (size_t)(kv0 + kw + lrow) * CC + 256 + d0);
#pragma unroll
            for (int qj = 0; qj < 4; ++qj) {
                short8 qfr = *(const short8*)(Qs + (qj * 16 + lrow) * QST + d0);
                accA[qj] = __builtin_amdgcn_mfma_f32_16x16x32_bf16(qfr, kfr, accA[qj], 0, 0, 0);
            }
        }
#pragma unroll
        for (int qj = 0; qj < 4; ++qj)
#pragma unroll
            for (int j = 0; j < 4; ++j) {
                float p = __expf(accA[qj][j] * 0.0625f);
                psum[qj][j] += p;
                P[(qj * 16 + hi * 4 + j) * PST + kw + lrow] = f2bu(p);
            }
        __syncthreads();
        // ---- O += P V^T ----
        __builtin_amdgcn_s_setprio(1);
#pragma unroll
        for (int ks = 0; ks < 4; ++ks) {
            const int kb = (ks << 5) + lhk;
            short8 pa[4];
#pragma unroll
            for (int qj = 0; qj < 4; ++qj)
                pa[qj] = *(const short8*)(P + (qj * 16 + lrow) * PST + kb);
#pragma unroll
            for (int ci = 0; ci < 4; ++ci) {
                short8 vf = *(const short8*)(xbn + (size_t)(cw + ci * 16 + lrow) * HWD + kv0 + kb);
#pragma unroll
                for (int qj = 0; qj < 4; ++qj)
                    accO[qj][ci] = __builtin_amdgcn_mfma_f32_16x16x32_bf16(pa[qj], vf, accO[qj][ci], 0, 0, 0);
            }
        }
        __builtin_amdgcn_s_setprio(0);
        __syncthreads();
    }

    // ---- row sums across waves ----
#pragma unroll
    for (int qj = 0; qj < 4; ++qj)
#pragma unroll
        for (int j = 0; j < 4; ++j) {
            float s = psum[qj][j];
            s += __shfl_xor(s, 1, 16);
            s += __shfl_xor(s, 2, 16);
            s += __shfl_xor(s, 4, 16);
            s += __shfl_xor(s, 8, 16);
            if (lrow == 0) atomicAdd(&rowsum[qj * 16 + hi * 4 + j], s);
        }
    __syncthreads();

    // ---- normalize -> Os (overlays Q/P) ----
    float inv[4][4];
#pragma unroll
    for (int qj = 0; qj < 4; ++qj)
#pragma unroll
        for (int j = 0; j < 4; ++j)
            inv[qj][j] = 1.f / rowsum[qj * 16 + hi * 4 + j];
    __syncthreads();                               // everyone read rowsum; Q/P dead
#pragma unroll
    for (int qj = 0; qj < 4; ++qj)
#pragma unroll
        for (int ci = 0; ci < 4; ++ci) {
            const int c = cw + (ci << 4) + lrow;
#pragma unroll
            for (int j = 0; j < 4; ++j)
                Os[(qj * 16 + hi * 4 + j) * OST + c] = f2bu(accO[qj][ci][j] * inv[qj][j]);
        }
    __syncthreads();

    // ---- fuse conv: out[n, o, q] = x + b_fuse[o] + W_fuse . O ----
    f32x4 accF[4][4];
#pragma unroll
    for (int mi = 0; mi < 4; ++mi)
#pragma unroll
        for (int qj = 0; qj < 4; ++qj) accF[mi][qj] = fz;
    const int ob = wave << 6;                      // wave's 64-output range
    for (int kt = 0; kt < 16; ++kt) {
        const int k0 = (kt << 5) + lhk;
        short8 bq[4];
#pragma unroll
        for (int qj = 0; qj < 4; ++qj)
            bq[qj] = *(const short8*)(Os + (qj * 16 + lrow) * OST + k0);
        __builtin_amdgcn_s_setprio(1);
#pragma unroll
        for (int mi = 0; mi < 4; ++mi) {
            short8 af = *(const short8*)(Wfuse + (size_t)(ob + (mi << 4) + lrow) * CC + k0);
#pragma unroll
            for (int qj = 0; qj < 4; ++qj)
                accF[mi][qj] = __builtin_amdgcn_mfma_f32_16x16x32_bf16(af, bq[qj], accF[mi][qj], 0, 0, 0);
        }
        __builtin_amdgcn_s_setprio(0);
    }
#pragma unroll
    for (int mi = 0; mi < 4; ++mi) {
#pragma unroll
        for (int j = 0; j < 4; ++j) {
            const int o = ob + (mi << 4) + hi * 4 + j;
            const float bias = bfu[o];
#pragma unroll
            for (int qj = 0; qj < 4; ++qj) {
                const int q = q0 + qj * 16 + lrow;
                const size_t idx = ((size_t)(n * CC + o)) * HWD + q;
                out[idx] = accF[mi][qj][j] + bias + x[idx];
            }
        }
    }
}

extern "C" void kernel_launch(void* const* d_in, const int* in_sizes, int n_in,
                              void* d_out, int out_size, void* d_ws, size_t ws_size,
                              hipStream_t stream) {
    const float* x  = (const float*)d_in[0];
    const float* Wt = (const float*)d_in[1];
    const float* bt = (const float*)d_in[2];
    const float* Wp = (const float*)d_in[3];
    const float* bp = (const float*)d_in[4];
    const float* Wf = (const float*)d_in[5];
    const float* bfu = (const float*)d_in[6];
    float* out = (float*)d_out;

    char* ws = (char*)d_ws;
    unsigned short* xt_xb = (unsigned short*)(ws);                 // 32 MB (xt, later xb)
    unsigned short* tp    = (unsigned short*)(ws + 33554432);      // 32 MB
    unsigned short* Wcat  = (unsigned short*)(ws + 67108864);      // 512 KB
    unsigned short* Wfuse = (unsigned short*)(ws + 67633152);      // 512 KB

    k_packw<<<dim3(1024), 256, 0, stream>>>(Wt, Wp, Wf, Wcat, Wfuse);
    k_prep <<<dim3(32, 16, 32), 256, 0, stream>>>(x, xt_xb);
    k_embed<<<dim3(256, 4), 256, 0, stream>>>(xt_xb, Wcat, bt, bp, tp);
    k_cast <<<dim3(8192), 256, 0, stream>>>(x, xt_xb);             // xb overwrites xt
    k_attn3<<<dim3(16, 32), 512, 0, stream>>>(tp, xt_xb, Wfuse, bfu, x, out);
}